// Round 1
// baseline (7300.621 us; speedup 1.0000x reference)
//
#include <hip/hip_runtime.h>
#include <hip/hip_bf16.h>

#define N_NODES 50000
#define DIM     256
#define NEXP    4
#define NLAYER  3
#define NEDGE   1600000
#define BN_EPS  1e-5f

// ---------------------------------------------------------------- utilities
static __device__ __forceinline__ float wave_reduce(float v) {
    #pragma unroll
    for (int off = 32; off; off >>= 1) v += __shfl_xor(v, off, 64);
    return v;
}

// ---------------------------------------------------------------- degrees
__global__ void k_deg(const int* __restrict__ src, const int* __restrict__ dst,
                      int* __restrict__ cnt_out, int* __restrict__ cnt_in) {
    int i = blockIdx.x * 256 + threadIdx.x;
    if (i < NEDGE) {
        atomicAdd(&cnt_out[src[i]], 1);
        atomicAdd(&cnt_in[dst[i]], 1);
    }
}

__global__ void k_norm(const int* __restrict__ cnt_out, const int* __restrict__ cnt_in,
                       float* __restrict__ nsrc, float* __restrict__ ndst) {
    int i = blockIdx.x * 256 + threadIdx.x;
    if (i < N_NODES) {
        nsrc[i] = rsqrtf(fmaxf((float)cnt_out[i], 1.f));
        ndst[i] = rsqrtf(fmaxf((float)cnt_in[i], 1.f));
    }
}

// exclusive scan of cnt_in -> offs (N+1), also copy to cursor
__global__ __launch_bounds__(1024) void k_scan(const int* __restrict__ cnt_in,
                                               int* __restrict__ offs,
                                               int* __restrict__ cursor) {
    __shared__ int ps[1024];
    const int CH = 49;                       // 1024*49 = 50176 >= 50000
    int t = threadIdx.x;
    int base = t * CH;
    int s = 0;
    for (int k = 0; k < CH; k++) { int i = base + k; if (i < N_NODES) s += cnt_in[i]; }
    ps[t] = s; __syncthreads();
    for (int off = 1; off < 1024; off <<= 1) {
        int v = ps[t];
        int u = (t >= off) ? ps[t - off] : 0;
        __syncthreads();
        ps[t] = v + u;
        __syncthreads();
    }
    int run = (t == 0) ? 0 : ps[t - 1];
    for (int k = 0; k < CH; k++) {
        int i = base + k;
        if (i < N_NODES) { offs[i] = run; cursor[i] = run; run += cnt_in[i]; }
    }
    if (t == 1023) offs[N_NODES] = ps[1023];
}

__global__ void k_fill(const int* __restrict__ src, const int* __restrict__ dst,
                       const float* __restrict__ nsrc,
                       int* __restrict__ cursor,
                       int* __restrict__ csr_s, float* __restrict__ csr_w) {
    int i = blockIdx.x * 256 + threadIdx.x;
    if (i < NEDGE) {
        int s = src[i], d = dst[i];
        int pos = atomicAdd(&cursor[d], 1);
        csr_s[pos] = s;
        csr_w[pos] = nsrc[s];
    }
}

// ---------------------------------------------------------------- embedding
__global__ void k_emb(const int* __restrict__ x, const float4* __restrict__ emb4,
                      float4* __restrict__ h4) {
    int i = blockIdx.x * 256 + threadIdx.x;   // N*64 float4s
    if (i < N_NODES * 64) {
        int n = i >> 6, c = i & 63;
        h4[i] = emb4[x[n] * 64 + c];
    }
}

// ---------------------------------------------------------------- gating (one wave / node)
__global__ void k_gate(const float4* __restrict__ h4, const float4* __restrict__ wg4,
                       int* __restrict__ bcount, int* __restrict__ bnode,
                       float* __restrict__ bgate) {
    int n    = blockIdx.x * 4 + (threadIdx.x >> 6);
    int lane = threadIdx.x & 63;
    if (n >= N_NODES) return;
    float4 hv = h4[n * 64 + lane];
    const float* hp = (const float*)&hv;
    float4 acc = {0.f, 0.f, 0.f, 0.f};
    #pragma unroll
    for (int j = 0; j < 4; j++) {
        float4 w = wg4[lane * 4 + j];   // w_gate[l][d][0..3]
        acc.x += hp[j] * w.x; acc.y += hp[j] * w.y;
        acc.z += hp[j] * w.z; acc.w += hp[j] * w.w;
    }
    acc.x = wave_reduce(acc.x); acc.y = wave_reduce(acc.y);
    acc.z = wave_reduce(acc.z); acc.w = wave_reduce(acc.w);
    if (lane == 0) {
        float lg[4] = {acc.x, acc.y, acc.z, acc.w};
        int e1 = 0;
        #pragma unroll
        for (int e = 1; e < 4; e++) if (lg[e] > lg[e1]) e1 = e;
        int e2 = -1;
        #pragma unroll
        for (int e = 0; e < 4; e++) {
            if (e == e1) continue;
            if (e2 < 0 || lg[e] > lg[e2]) e2 = e;
        }
        float v1 = lg[e1], v2 = lg[e2];
        float g2 = 1.f / (1.f + expf(v1 - v2));   // softmax over {v1,v2}
        float g1 = 1.f - g2;
        int p1 = atomicAdd(&bcount[e1], 1);
        bnode[e1 * N_NODES + p1] = n; bgate[e1 * N_NODES + p1] = g1;
        int p2 = atomicAdd(&bcount[e2], 1);
        bnode[e2 * N_NODES + p2] = n; bgate[e2 * N_NODES + p2] = g2;
    }
}

// ---------------------------------------------------------------- aggregation (one wave / dst)
__global__ void k_agg(const float4* __restrict__ h4,
                      const int* __restrict__ offs,
                      const int* __restrict__ csr_s, const float* __restrict__ csr_w,
                      const float* __restrict__ ndst,
                      float4* __restrict__ agg4) {
    int n    = blockIdx.x * 4 + (threadIdx.x >> 6);
    int lane = threadIdx.x & 63;
    if (n >= N_NODES) return;
    int beg = offs[n], end = offs[n + 1];
    float4 acc = {0.f, 0.f, 0.f, 0.f};
    for (int j = beg; j < end; j++) {
        int   s = csr_s[j];
        float w = csr_w[j];
        float4 hv = h4[s * 64 + lane];
        acc.x += w * hv.x; acc.y += w * hv.y; acc.z += w * hv.z; acc.w += w * hv.w;
    }
    float nd = ndst[n];
    acc.x *= nd; acc.y *= nd; acc.z *= nd; acc.w *= nd;
    agg4[n * 64 + lane] = acc;
}

// ---------------------------------------------------------------- column sums of agg
__global__ void k_colsum(const float* __restrict__ agg, float* __restrict__ msum) {
    int t = threadIdx.x;                       // 256 threads == 256 columns
    const int CH = 391;                        // 128*391 >= 50000
    int n0 = blockIdx.x * CH;
    float s = 0.f;
    for (int r = 0; r < CH; r++) {
        int n = n0 + r;
        if (n < N_NODES) s += agg[n * DIM + t];
    }
    atomicAdd(&msum[t], s);
}

// ---------------------------------------------------------------- Gram C = agg^T agg
#define GK     32
#define GCHUNK 1568   // 32*1568 = 50176 >= 50000 ; 1568 = 98*16
__global__ __launch_bounds__(256) void k_gram(const float* __restrict__ agg,
                                              float* __restrict__ C) {
    __shared__ float LA[16][64];
    __shared__ float LB[16][64];
    int tid = threadIdx.x;
    int ti = blockIdx.y >> 2, tj = blockIdx.y & 3;
    int tx = tid & 15, ty = tid >> 4;
    float acc[4][4] = {};
    int nbase = blockIdx.x * GCHUNK;
    for (int s0 = 0; s0 < GCHUNK; s0 += 16) {
        #pragma unroll
        for (int q = 0; q < 8; q++) {
            int idx  = tid + q * 256;          // 0..2047
            int r    = idx >> 7;
            int half = (idx >> 6) & 1;
            int c    = idx & 63;
            int n    = nbase + s0 + r;
            float v  = 0.f;
            if (n < N_NODES) v = agg[n * DIM + (half ? tj : ti) * 64 + c];
            if (half) LB[r][c] = v; else LA[r][c] = v;
        }
        __syncthreads();
        #pragma unroll
        for (int r = 0; r < 16; r++) {
            float4 av = *(const float4*)&LA[r][tx * 4];
            float4 bv = *(const float4*)&LB[r][ty * 4];
            const float* af = (const float*)&av;
            const float* bf = (const float*)&bv;
            #pragma unroll
            for (int i = 0; i < 4; i++)
                #pragma unroll
                for (int j = 0; j < 4; j++)
                    acc[i][j] += af[i] * bf[j];
        }
        __syncthreads();
    }
    #pragma unroll
    for (int i = 0; i < 4; i++)
        #pragma unroll
        for (int j = 0; j < 4; j++)
            atomicAdd(&C[(ti * 64 + tx * 4 + i) * DIM + tj * 64 + ty * 4 + j], acc[i][j]);
}

// ---------------------------------------------------------------- BN stats -> scale/shift
__global__ __launch_bounds__(256) void k_stats(const float* __restrict__ C,
                                               const float* __restrict__ msum,
                                               const float* __restrict__ conv_W,
                                               const float* __restrict__ bn_gamma,
                                               const float* __restrict__ bn_beta,
                                               float* __restrict__ scaleb,
                                               float* __restrict__ shiftb, int l) {
    int e = blockIdx.x >> 8, f = blockIdx.x & 255;
    int t = threadIdx.x;
    __shared__ float wsh[256];
    __shared__ float red[256];
    const float* W = conv_W + (size_t)(l * NEXP + e) * DIM * DIM;  // [d][f]
    wsh[t] = W[t * DIM + f];
    __syncthreads();
    float v = 0.f;
    #pragma unroll 8
    for (int d2 = 0; d2 < DIM; d2++) v += C[d2 * DIM + t] * wsh[d2];  // C symmetric: column read
    float a_t = msum[t] * (1.f / (float)N_NODES);
    float qp  = wsh[t] * v;
    float ap  = a_t * wsh[t];
    red[t] = qp; __syncthreads();
    for (int off = 128; off; off >>= 1) { if (t < off) red[t] += red[t + off]; __syncthreads(); }
    float q = red[0];                       // only t==0 uses it
    red[t] = ap; __syncthreads();
    for (int off = 128; off; off >>= 1) { if (t < off) red[t] += red[t + off]; __syncthreads(); }
    if (t == 0) {
        float aw  = red[0];
        float var = q * (1.f / (float)N_NODES) - aw * aw;
        var = fmaxf(var, 0.f);
        float sg = bn_gamma[(l * NEXP + e) * DIM + f] * rsqrtf(var + BN_EPS);
        scaleb[e * DIM + f] = sg;
        shiftb[e * DIM + f] = bn_beta[(l * NEXP + e) * DIM + f] - aw * sg;
    }
}

__global__ void k_wscale(const float* __restrict__ conv_W, const float* __restrict__ scaleb,
                         float* __restrict__ Ws, int l) {
    int i = blockIdx.x * 256 + threadIdx.x;     // NEXP*DIM*DIM
    if (i < NEXP * DIM * DIM) {
        int e = i >> 16, f = i & 255;
        Ws[i] = conv_W[(size_t)l * NEXP * DIM * DIM + i] * scaleb[e * DIM + f];
    }
}

// ---------------------------------------------------------------- grouped expert GEMM
#define TM 32
__global__ __launch_bounds__(256) void k_gemm(const float* __restrict__ agg,
                                              const float* __restrict__ Ws,
                                              const float* __restrict__ shiftb,
                                              const int* __restrict__ bcount,
                                              const int* __restrict__ bnode,
                                              const float* __restrict__ bgate,
                                              float* __restrict__ hout) {
    __shared__ int   nds[TM];
    __shared__ float gds[TM];
    __shared__ float A[TM][DIM];     // 32 KB
    __shared__ float WB[16][DIM];    // 16 KB
    int e    = blockIdx.y;
    int base = blockIdx.x * TM;
    int cnt  = bcount[e];
    if (base >= cnt) return;
    int t = threadIdx.x;
    if (t < TM) {
        int idx = base + t;
        if (idx < cnt) { nds[t] = bnode[e * N_NODES + idx]; gds[t] = bgate[e * N_NODES + idx]; }
        else           { nds[t] = -1;                        gds[t] = 0.f; }
    }
    __syncthreads();
    {   // stage A tile (gathered agg rows)
        const float4* agg4 = (const float4*)agg;
        float4* A4 = (float4*)A;
        #pragma unroll
        for (int q = 0; q < TM * 64 / 256; q++) {
            int idx = t + q * 256;
            int r = idx >> 6, c = idx & 63;
            int n = nds[r];
            float4 v = {0.f, 0.f, 0.f, 0.f};
            if (n >= 0) v = agg4[n * 64 + c];
            A4[idx] = v;
        }
    }
    __syncthreads();
    int rg = t >> 4, cg = t & 15;
    int r0 = rg * 2;
    int c0 = cg * 16;
    float acc[2][16] = {};
    const float* We = Ws + e * DIM * DIM;
    for (int db = 0; db < DIM; db += 16) {
        {   // stage 16 rows of W
            const float4* W4 = (const float4*)(We + db * DIM);
            float4* WB4 = (float4*)WB;
            #pragma unroll
            for (int q = 0; q < 4; q++) WB4[t + q * 256] = W4[t + q * 256];
        }
        __syncthreads();
        #pragma unroll 4
        for (int dd = 0; dd < 16; dd++) {
            float a0 = A[r0][db + dd];
            float a1 = A[r0 + 1][db + dd];
            const float4* wr = (const float4*)&WB[dd][c0];
            float4 w0 = wr[0], w1 = wr[1], w2 = wr[2], w3 = wr[3];
            const float* wf0 = (const float*)&w0;
            const float* wf1 = (const float*)&w1;
            const float* wf2 = (const float*)&w2;
            const float* wf3 = (const float*)&w3;
            #pragma unroll
            for (int k = 0; k < 4; k++) {
                acc[0][k]      += a0 * wf0[k];  acc[1][k]      += a1 * wf0[k];
                acc[0][4 + k]  += a0 * wf1[k];  acc[1][4 + k]  += a1 * wf1[k];
                acc[0][8 + k]  += a0 * wf2[k];  acc[1][8 + k]  += a1 * wf2[k];
                acc[0][12 + k] += a0 * wf3[k];  acc[1][12 + k] += a1 * wf3[k];
            }
        }
        __syncthreads();
    }
    // write acc back to LDS for a coalesced atomic epilogue
    #pragma unroll
    for (int j = 0; j < 2; j++)
        #pragma unroll
        for (int k = 0; k < 16; k++)
            A[r0 + j][c0 + k] = acc[j][k];
    __syncthreads();
    for (int q = 0; q < TM * DIM / 256; q++) {   // 32 coalesced passes
        int idx = t + q * 256;
        int r = idx >> 8, c = idx & 255;
        int n = nds[r];
        if (n >= 0) {
            float g = gds[r];
            atomicAdd(&hout[n * DIM + c], g * (A[r][c] + shiftb[e * DIM + c]));
        }
    }
}

// ---------------------------------------------------------------- h = v + relu(v)
__global__ void k_relu(float4* __restrict__ h) {
    int i = blockIdx.x * 256 + threadIdx.x;
    if (i < N_NODES * 64) {
        float4 v = h[i];
        v.x += fmaxf(v.x, 0.f); v.y += fmaxf(v.y, 0.f);
        v.z += fmaxf(v.z, 0.f); v.w += fmaxf(v.w, 0.f);
        h[i] = v;
    }
}

// ================================================================ host
extern "C" void kernel_launch(void* const* d_in, const int* in_sizes, int n_in,
                              void* d_out, int out_size, void* d_ws, size_t ws_size,
                              hipStream_t stream) {
    const int*   x        = (const int*)d_in[0];
    const int*   ei       = (const int*)d_in[1];
    const float* emb      = (const float*)d_in[2];
    const float* w_gate   = (const float*)d_in[3];
    const float* conv_W   = (const float*)d_in[4];
    // conv_b (d_in[5]) cancels exactly in the BN fold — unused
    const float* bn_gamma = (const float*)d_in[6];
    const float* bn_beta  = (const float*)d_in[7];
    float* out = (float*)d_out;

    const int* src = ei;
    const int* dst = ei + NEDGE;

    char* ws = (char*)d_ws;
    size_t off = 0;
    auto alloc = [&](size_t bytes) -> void* {
        void* p = ws + off;
        off += (bytes + 255) & ~(size_t)255;
        return p;
    };
    float* h_a      = (float*)alloc((size_t)N_NODES * DIM * 4);
    float* h_b      = (float*)alloc((size_t)N_NODES * DIM * 4);
    float* agg      = (float*)alloc((size_t)N_NODES * DIM * 4);
    int*   cnt_out  = (int*)  alloc((size_t)N_NODES * 4);
    int*   cnt_in   = (int*)  alloc((size_t)N_NODES * 4);
    float* nsrc     = (float*)alloc((size_t)N_NODES * 4);
    float* ndst     = (float*)alloc((size_t)N_NODES * 4);
    int*   offs     = (int*)  alloc((size_t)(N_NODES + 1) * 4);
    int*   cursor   = (int*)  alloc((size_t)N_NODES * 4);
    int*   csr_s    = (int*)  alloc((size_t)NEDGE * 4);
    float* csr_w    = (float*)alloc((size_t)NEDGE * 4);
    int*   bcount   = (int*)  alloc(NEXP * 4);
    int*   bnode    = (int*)  alloc((size_t)NEXP * N_NODES * 4);
    float* bgate    = (float*)alloc((size_t)NEXP * N_NODES * 4);
    float* Cm       = (float*)alloc((size_t)DIM * DIM * 4);
    float* msum     = (float*)alloc((size_t)DIM * 4);
    float* scaleb   = (float*)alloc((size_t)NEXP * DIM * 4);
    float* shiftb   = (float*)alloc((size_t)NEXP * DIM * 4);
    float* Wsbuf    = (float*)alloc((size_t)NEXP * DIM * DIM * 4);
    (void)ws_size; (void)in_sizes; (void)n_in; (void)out_size;

    // ---- graph structure (per call; inputs are restored every call)
    hipMemsetAsync(cnt_out, 0, (size_t)N_NODES * 4, stream);
    hipMemsetAsync(cnt_in,  0, (size_t)N_NODES * 4, stream);
    k_deg <<<(NEDGE + 255) / 256, 256, 0, stream>>>(src, dst, cnt_out, cnt_in);
    k_norm<<<(N_NODES + 255) / 256, 256, 0, stream>>>(cnt_out, cnt_in, nsrc, ndst);
    k_scan<<<1, 1024, 0, stream>>>(cnt_in, offs, cursor);
    k_fill<<<(NEDGE + 255) / 256, 256, 0, stream>>>(src, dst, nsrc, cursor, csr_s, csr_w);
    k_emb <<<(N_NODES * 64 + 255) / 256, 256, 0, stream>>>(x, (const float4*)emb, (float4*)h_a);

    float* hin = h_a;
    for (int l = 0; l < NLAYER; l++) {
        float* hout = (l == NLAYER - 1) ? out : ((l & 1) ? h_a : h_b);

        hipMemsetAsync(bcount, 0, NEXP * 4, stream);
        k_gate<<<N_NODES / 4, 256, 0, stream>>>((const float4*)hin,
                (const float4*)(w_gate + (size_t)l * DIM * NEXP), bcount, bnode, bgate);
        k_agg<<<N_NODES / 4, 256, 0, stream>>>((const float4*)hin, offs, csr_s, csr_w,
                ndst, (float4*)agg);

        hipMemsetAsync(Cm,   0, (size_t)DIM * DIM * 4, stream);
        hipMemsetAsync(msum, 0, (size_t)DIM * 4, stream);
        k_colsum<<<128, 256, 0, stream>>>(agg, msum);
        k_gram<<<dim3(GK, 16), 256, 0, stream>>>(agg, Cm);
        k_stats<<<NEXP * DIM, 256, 0, stream>>>(Cm, msum, conv_W, bn_gamma, bn_beta,
                                                scaleb, shiftb, l);
        k_wscale<<<(NEXP * DIM * DIM + 255) / 256, 256, 0, stream>>>(conv_W, scaleb, Wsbuf, l);

        hipMemsetAsync(hout, 0, (size_t)N_NODES * DIM * 4, stream);
        k_gemm<<<dim3((N_NODES + TM - 1) / TM, NEXP), 256, 0, stream>>>(agg, Wsbuf, shiftb,
                bcount, bnode, bgate, hout);
        k_relu<<<(N_NODES * 64 + 255) / 256, 256, 0, stream>>>((float4*)hout);

        hin = hout;
    }
}

// Round 2
// 2943.148 us; speedup vs baseline: 2.4805x; 2.4805x over previous
//
#include <hip/hip_runtime.h>
#include <hip/hip_bf16.h>

#define N_NODES 50000
#define DIM     256
#define NEXP    4
#define NLAYER  3
#define NEDGE   1600000
#define BN_EPS  1e-5f

// ---------------------------------------------------------------- utilities
static __device__ __forceinline__ float wave_reduce(float v) {
    #pragma unroll
    for (int off = 32; off; off >>= 1) v += __shfl_xor(v, off, 64);
    return v;
}

// ---------------------------------------------------------------- degrees
__global__ void k_deg(const int* __restrict__ src, const int* __restrict__ dst,
                      int* __restrict__ cnt_out, int* __restrict__ cnt_in) {
    int i = blockIdx.x * 256 + threadIdx.x;
    if (i < NEDGE) {
        atomicAdd(&cnt_out[src[i]], 1);
        atomicAdd(&cnt_in[dst[i]], 1);
    }
}

__global__ void k_norm(const int* __restrict__ cnt_out, const int* __restrict__ cnt_in,
                       float* __restrict__ nsrc, float* __restrict__ ndst) {
    int i = blockIdx.x * 256 + threadIdx.x;
    if (i < N_NODES) {
        nsrc[i] = rsqrtf(fmaxf((float)cnt_out[i], 1.f));
        ndst[i] = rsqrtf(fmaxf((float)cnt_in[i], 1.f));
    }
}

// exclusive scan of cnt_in -> offs (N+1), also copy to cursor
__global__ __launch_bounds__(1024) void k_scan(const int* __restrict__ cnt_in,
                                               int* __restrict__ offs,
                                               int* __restrict__ cursor) {
    __shared__ int ps[1024];
    const int CH = 49;                       // 1024*49 = 50176 >= 50000
    int t = threadIdx.x;
    int base = t * CH;
    int s = 0;
    for (int k = 0; k < CH; k++) { int i = base + k; if (i < N_NODES) s += cnt_in[i]; }
    ps[t] = s; __syncthreads();
    for (int off = 1; off < 1024; off <<= 1) {
        int v = ps[t];
        int u = (t >= off) ? ps[t - off] : 0;
        __syncthreads();
        ps[t] = v + u;
        __syncthreads();
    }
    int run = (t == 0) ? 0 : ps[t - 1];
    for (int k = 0; k < CH; k++) {
        int i = base + k;
        if (i < N_NODES) { offs[i] = run; cursor[i] = run; run += cnt_in[i]; }
    }
    if (t == 1023) offs[N_NODES] = ps[1023];
}

__global__ void k_fill(const int* __restrict__ src, const int* __restrict__ dst,
                       const float* __restrict__ nsrc,
                       int* __restrict__ cursor,
                       int* __restrict__ csr_s, float* __restrict__ csr_w) {
    int i = blockIdx.x * 256 + threadIdx.x;
    if (i < NEDGE) {
        int s = src[i], d = dst[i];
        int pos = atomicAdd(&cursor[d], 1);
        csr_s[pos] = s;
        csr_w[pos] = nsrc[s];
    }
}

// ---------------------------------------------------------------- embedding
__global__ void k_emb(const int* __restrict__ x, const float4* __restrict__ emb4,
                      float4* __restrict__ h4) {
    int i = blockIdx.x * 256 + threadIdx.x;   // N*64 float4s
    if (i < N_NODES * 64) {
        int n = i >> 6, c = i & 63;
        h4[i] = emb4[x[n] * 64 + c];
    }
}

// ---------------------------------------------------------------- gating: dense gates[N] float4, NO atomics
__global__ void k_gate(const float4* __restrict__ h4, const float4* __restrict__ wg4,
                       float4* __restrict__ gates) {
    int n    = blockIdx.x * 4 + (threadIdx.x >> 6);
    int lane = threadIdx.x & 63;
    if (n >= N_NODES) return;
    float4 hv = h4[n * 64 + lane];
    const float* hp = (const float*)&hv;
    float4 acc = {0.f, 0.f, 0.f, 0.f};
    #pragma unroll
    for (int j = 0; j < 4; j++) {
        float4 w = wg4[lane * 4 + j];   // w_gate[l][d][0..3]
        acc.x += hp[j] * w.x; acc.y += hp[j] * w.y;
        acc.z += hp[j] * w.z; acc.w += hp[j] * w.w;
    }
    acc.x = wave_reduce(acc.x); acc.y = wave_reduce(acc.y);
    acc.z = wave_reduce(acc.z); acc.w = wave_reduce(acc.w);
    if (lane == 0) {
        float lg[4] = {acc.x, acc.y, acc.z, acc.w};
        int e1 = 0;
        #pragma unroll
        for (int e = 1; e < 4; e++) if (lg[e] > lg[e1]) e1 = e;
        int e2 = -1;
        #pragma unroll
        for (int e = 0; e < 4; e++) {
            if (e == e1) continue;
            if (e2 < 0 || lg[e] > lg[e2]) e2 = e;
        }
        float v1 = lg[e1], v2 = lg[e2];
        float g2 = 1.f / (1.f + expf(v1 - v2));   // softmax over {v1,v2}
        float g1 = 1.f - g2;
        float g[4] = {0.f, 0.f, 0.f, 0.f};
        g[e1] = g1; g[e2] = g2;
        float4 gv; gv.x = g[0]; gv.y = g[1]; gv.z = g[2]; gv.w = g[3];
        gates[n] = gv;
    }
}

// ---------------------------------------------------------------- aggregation (one wave / dst)
__global__ void k_agg(const float4* __restrict__ h4,
                      const int* __restrict__ offs,
                      const int* __restrict__ csr_s, const float* __restrict__ csr_w,
                      const float* __restrict__ ndst,
                      float4* __restrict__ agg4) {
    int n    = blockIdx.x * 4 + (threadIdx.x >> 6);
    int lane = threadIdx.x & 63;
    if (n >= N_NODES) return;
    int beg = offs[n], end = offs[n + 1];
    float4 acc = {0.f, 0.f, 0.f, 0.f};
    for (int j = beg; j < end; j++) {
        int   s = csr_s[j];
        float w = csr_w[j];
        float4 hv = h4[s * 64 + lane];
        acc.x += w * hv.x; acc.y += w * hv.y; acc.z += w * hv.z; acc.w += w * hv.w;
    }
    float nd = ndst[n];
    acc.x *= nd; acc.y *= nd; acc.z *= nd; acc.w *= nd;
    agg4[n * 64 + lane] = acc;
}

// ---------------------------------------------------------------- column sums of agg
__global__ void k_colsum(const float* __restrict__ agg, float* __restrict__ msum) {
    int t = threadIdx.x;                       // 256 threads == 256 columns
    const int CH = 391;                        // 128*391 >= 50000
    int n0 = blockIdx.x * CH;
    float s = 0.f;
    for (int r = 0; r < CH; r++) {
        int n = n0 + r;
        if (n < N_NODES) s += agg[n * DIM + t];
    }
    atomicAdd(&msum[t], s);
}

// ---------------------------------------------------------------- Gram partials: Cp[sl][pair][64][64]
#define GSL 64     // k-slices
#define GCH 784    // rows per slice: 64*784 = 50176 >= 50000 ; 784 = 49*16
__global__ __launch_bounds__(256) void k_gram(const float* __restrict__ agg,
                                              float* __restrict__ Cp) {
    __shared__ float LA[16][64];
    __shared__ float LB[16][64];
    int t  = threadIdx.x;
    int sl = blockIdx.x;            // k-slice
    int pr = blockIdx.y;            // tile pair 0..15
    int ti = pr >> 2, tj = pr & 3;
    int tx = t & 15, ty = t >> 4;
    float acc[4][4] = {};
    int nbase = sl * GCH;
    const float4* agg4 = (const float4*)agg;
    for (int s0 = 0; s0 < GCH; s0 += 16) {
        int r = ty;                  // 16 rows staged, one per thread group
        int n = nbase + s0 + r;
        float4 va = {0.f, 0.f, 0.f, 0.f}, vb = {0.f, 0.f, 0.f, 0.f};
        if (n < N_NODES) {
            va = agg4[n * 64 + ti * 16 + tx];
            vb = agg4[n * 64 + tj * 16 + tx];
        }
        __syncthreads();
        *(float4*)&LA[r][tx * 4] = va;
        *(float4*)&LB[r][tx * 4] = vb;
        __syncthreads();
        #pragma unroll
        for (int rr = 0; rr < 16; rr++) {
            float4 a = *(const float4*)&LA[rr][tx * 4];   // 2 lanes/bank: free
            float4 b = *(const float4*)&LB[rr][ty * 4];   // broadcast within quarter
            const float* af = (const float*)&a;
            const float* bf = (const float*)&b;
            #pragma unroll
            for (int i = 0; i < 4; i++)
                #pragma unroll
                for (int j = 0; j < 4; j++)
                    acc[i][j] += af[i] * bf[j];
        }
    }
    float* Cb = Cp + ((size_t)(sl * 16 + pr)) * 4096;
    #pragma unroll
    for (int i = 0; i < 4; i++) {
        float4 v; v.x = acc[i][0]; v.y = acc[i][1]; v.z = acc[i][2]; v.w = acc[i][3];
        *(float4*)&Cb[(tx * 4 + i) * 64 + ty * 4] = v;
    }
}

__global__ void k_gred(const float* __restrict__ Cp, float* __restrict__ Cm) {
    int gid = blockIdx.x * 256 + threadIdx.x;    // 65536
    int i = gid >> 8, j = gid & 255;
    int pr = (i >> 6) * 4 + (j >> 6);
    const float* p = Cp + (size_t)pr * 4096 + (i & 63) * 64 + (j & 63);
    float s = 0.f;
    #pragma unroll 8
    for (int sl = 0; sl < GSL; sl++) s += p[(size_t)sl * 16 * 4096];
    Cm[gid] = s;
}

// ---------------------------------------------------------------- BN stats -> scale/shift
__global__ __launch_bounds__(256) void k_stats(const float* __restrict__ C,
                                               const float* __restrict__ msum,
                                               const float* __restrict__ conv_W,
                                               const float* __restrict__ bn_gamma,
                                               const float* __restrict__ bn_beta,
                                               float* __restrict__ scaleb,
                                               float* __restrict__ shiftb, int l) {
    int e = blockIdx.x >> 8, f = blockIdx.x & 255;
    int t = threadIdx.x;
    __shared__ float wsh[256];
    __shared__ float red[256];
    const float* W = conv_W + (size_t)(l * NEXP + e) * DIM * DIM;  // [d][f]
    wsh[t] = W[t * DIM + f];
    __syncthreads();
    float v = 0.f;
    #pragma unroll 8
    for (int d2 = 0; d2 < DIM; d2++) v += C[d2 * DIM + t] * wsh[d2];  // C symmetric: column read
    float a_t = msum[t] * (1.f / (float)N_NODES);
    float qp  = wsh[t] * v;
    float ap  = a_t * wsh[t];
    red[t] = qp; __syncthreads();
    for (int off = 128; off; off >>= 1) { if (t < off) red[t] += red[t + off]; __syncthreads(); }
    float q = red[0];                       // only t==0 uses it
    red[t] = ap; __syncthreads();
    for (int off = 128; off; off >>= 1) { if (t < off) red[t] += red[t + off]; __syncthreads(); }
    if (t == 0) {
        float aw  = red[0];
        float var = q * (1.f / (float)N_NODES) - aw * aw;
        var = fmaxf(var, 0.f);
        float sg = bn_gamma[(l * NEXP + e) * DIM + f] * rsqrtf(var + BN_EPS);
        scaleb[e * DIM + f] = sg;
        shiftb[e * DIM + f] = bn_beta[(l * NEXP + e) * DIM + f] - aw * sg;
    }
}

__global__ void k_wscale(const float* __restrict__ conv_W, const float* __restrict__ scaleb,
                         float* __restrict__ Ws, int l) {
    int i = blockIdx.x * 256 + threadIdx.x;     // NEXP*DIM*DIM
    if (i < NEXP * DIM * DIM) {
        int e = i >> 16, f = i & 255;
        Ws[i] = conv_W[(size_t)l * NEXP * DIM * DIM + i] * scaleb[e * DIM + f];
    }
}

// ---------------------------------------------------------------- fused dense-4 MoE GEMM
// h_out[n,f] = v + relu(v), v = sum_e g[n,e]*(agg[n,:]·Ws[e,:,f] + shift[e,f])
// Gates folded into A: one K=1024 GEMM accumulating across experts in-register.
__global__ __launch_bounds__(256) void k_moe(const float4* __restrict__ agg4,
                                             const float4* __restrict__ gates,
                                             const float* __restrict__ Ws,
                                             const float* __restrict__ shiftb,
                                             float* __restrict__ hout) {
    __shared__ float As[64][16];     // 4 KB (A' slab, gate-scaled)
    __shared__ float WB[16][256];    // 16 KB
    __shared__ float gl[64][4];      // gates tile
    __shared__ float sh[4][256];     // shifts, all experts
    int t    = threadIdx.x;
    int base = blockIdx.x * 64;
    if (t < 64) {
        int n = base + t;
        float4 g = {0.f, 0.f, 0.f, 0.f};
        if (n < N_NODES) g = gates[n];
        gl[t][0] = g.x; gl[t][1] = g.y; gl[t][2] = g.z; gl[t][3] = g.w;
    }
    ((float4*)sh)[t] = ((const float4*)shiftb)[t];   // 1024 floats = 256 float4
    __syncthreads();

    int rg = t >> 4, cg = t & 15;
    int r0 = rg * 4, c4 = cg * 4;
    int rA = t >> 2, cA = t & 3;     // staging: row rA, float4-chunk cA
    int nA = base + rA;
    bool vA = (nA < N_NODES);
    float acc[4][16] = {};

    for (int db = 0; db < NEXP * DIM; db += 16) {
        int e  = db >> 8;
        int kk = db & 255;
        float4 av = {0.f, 0.f, 0.f, 0.f};
        if (vA) {
            av = agg4[nA * 64 + (kk >> 2) + cA];
            float g = gl[rA][e];
            av.x *= g; av.y *= g; av.z *= g; av.w *= g;
        }
        const float4* W4 = (const float4*)(Ws + (e << 16) + (kk << 8));
        float4 w0 = W4[t], w1 = W4[t + 256], w2 = W4[t + 512], w3 = W4[t + 768];
        __syncthreads();                  // previous iter's reads done
        ((float4*)As)[t] = av;            // As[rA][cA*4..+4]
        float4* WB4 = (float4*)WB;
        WB4[t] = w0; WB4[t + 256] = w1; WB4[t + 512] = w2; WB4[t + 768] = w3;
        __syncthreads();
        #pragma unroll
        for (int dd = 0; dd < 16; dd++) {
            float a0 = As[r0 + 0][dd];    // broadcast within quarter
            float a1 = As[r0 + 1][dd];
            float a2 = As[r0 + 2][dd];
            float a3 = As[r0 + 3][dd];
            #pragma unroll
            for (int q = 0; q < 4; q++) {
                float4 w = *(const float4*)&WB[dd][q * 64 + c4];   // 2 lanes/bank: free
                const float* wf = (const float*)&w;
                #pragma unroll
                for (int k = 0; k < 4; k++) {
                    acc[0][q * 4 + k] += a0 * wf[k];
                    acc[1][q * 4 + k] += a1 * wf[k];
                    acc[2][q * 4 + k] += a2 * wf[k];
                    acc[3][q * 4 + k] += a3 * wf[k];
                }
            }
        }
    }
    // epilogue: + sum_e g*shift, residual relu, direct store
    #pragma unroll
    for (int j = 0; j < 4; j++) {
        int n = base + r0 + j;
        if (n >= N_NODES) continue;
        float g0 = gl[r0 + j][0], g1 = gl[r0 + j][1];
        float g2 = gl[r0 + j][2], g3 = gl[r0 + j][3];
        #pragma unroll
        for (int q = 0; q < 4; q++) {
            int col = q * 64 + c4;
            float4 o;
            float* of = (float*)&o;
            #pragma unroll
            for (int k = 0; k < 4; k++) {
                float v = acc[j][q * 4 + k]
                        + g0 * sh[0][col + k] + g1 * sh[1][col + k]
                        + g2 * sh[2][col + k] + g3 * sh[3][col + k];
                of[k] = v + fmaxf(v, 0.f);
            }
            *(float4*)(hout + (size_t)n * DIM + col) = o;
        }
    }
}

// ================================================================ host
extern "C" void kernel_launch(void* const* d_in, const int* in_sizes, int n_in,
                              void* d_out, int out_size, void* d_ws, size_t ws_size,
                              hipStream_t stream) {
    const int*   x        = (const int*)d_in[0];
    const int*   ei       = (const int*)d_in[1];
    const float* emb      = (const float*)d_in[2];
    const float* w_gate   = (const float*)d_in[3];
    const float* conv_W   = (const float*)d_in[4];
    // conv_b (d_in[5]) cancels exactly in the BN fold — unused
    const float* bn_gamma = (const float*)d_in[6];
    const float* bn_beta  = (const float*)d_in[7];
    float* out = (float*)d_out;

    const int* src = ei;
    const int* dst = ei + NEDGE;

    char* ws = (char*)d_ws;
    size_t off = 0;
    auto alloc = [&](size_t bytes) -> void* {
        void* p = ws + off;
        off += (bytes + 255) & ~(size_t)255;
        return p;
    };
    float* h        = (float*)alloc((size_t)N_NODES * DIM * 4);   // single h buffer (in-place layers)
    float* agg      = (float*)alloc((size_t)N_NODES * DIM * 4);
    int*   cnt_out  = (int*)  alloc((size_t)N_NODES * 4);
    int*   cnt_in   = (int*)  alloc((size_t)N_NODES * 4);
    float* nsrc     = (float*)alloc((size_t)N_NODES * 4);
    float* ndst     = (float*)alloc((size_t)N_NODES * 4);
    int*   offs     = (int*)  alloc((size_t)(N_NODES + 1) * 4);
    int*   cursor   = (int*)  alloc((size_t)N_NODES * 4);
    int*   csr_s    = (int*)  alloc((size_t)NEDGE * 4);
    float* csr_w    = (float*)alloc((size_t)NEDGE * 4);
    float* gates    = (float*)alloc((size_t)N_NODES * 4 * 4);
    float* Cp       = (float*)alloc((size_t)GSL * 16 * 4096 * 4); // 16.8 MB gram partials
    float* Cm       = (float*)alloc((size_t)DIM * DIM * 4);
    float* msum     = (float*)alloc((size_t)DIM * 4);
    float* scaleb   = (float*)alloc((size_t)NEXP * DIM * 4);
    float* shiftb   = (float*)alloc((size_t)NEXP * DIM * 4);
    float* Wsbuf    = (float*)alloc((size_t)NEXP * DIM * DIM * 4);
    (void)ws_size; (void)in_sizes; (void)n_in; (void)out_size;

    // ---- graph structure (per call; inputs are restored every call)
    hipMemsetAsync(cnt_out, 0, (size_t)N_NODES * 4, stream);
    hipMemsetAsync(cnt_in,  0, (size_t)N_NODES * 4, stream);
    k_deg <<<(NEDGE + 255) / 256, 256, 0, stream>>>(src, dst, cnt_out, cnt_in);
    k_norm<<<(N_NODES + 255) / 256, 256, 0, stream>>>(cnt_out, cnt_in, nsrc, ndst);
    k_scan<<<1, 1024, 0, stream>>>(cnt_in, offs, cursor);
    k_fill<<<(NEDGE + 255) / 256, 256, 0, stream>>>(src, dst, nsrc, cursor, csr_s, csr_w);
    k_emb <<<(N_NODES * 64 + 255) / 256, 256, 0, stream>>>(x, (const float4*)emb, (float4*)h);

    for (int l = 0; l < NLAYER; l++) {
        float* hout = (l == NLAYER - 1) ? out : h;   // k_moe reads only agg+gates: in-place OK

        k_gate<<<N_NODES / 4, 256, 0, stream>>>((const float4*)h,
                (const float4*)(w_gate + (size_t)l * DIM * NEXP), (float4*)gates);
        k_agg<<<N_NODES / 4, 256, 0, stream>>>((const float4*)h, offs, csr_s, csr_w,
                ndst, (float4*)agg);

        hipMemsetAsync(msum, 0, (size_t)DIM * 4, stream);
        k_colsum<<<128, 256, 0, stream>>>(agg, msum);
        k_gram<<<dim3(GSL, 16), 256, 0, stream>>>(agg, Cp);
        k_gred<<<DIM * DIM / 256, 256, 0, stream>>>(Cp, Cm);
        k_stats<<<NEXP * DIM, 256, 0, stream>>>(Cm, msum, conv_W, bn_gamma, bn_beta,
                                                scaleb, shiftb, l);
        k_wscale<<<(NEXP * DIM * DIM + 255) / 256, 256, 0, stream>>>(conv_W, scaleb, Wsbuf, l);

        k_moe<<<(N_NODES + 63) / 64, 256, 0, stream>>>((const float4*)agg, (const float4*)gates,
                Wsbuf, shiftb, hout);
    }
}